// Round 4
// baseline (239.113 us; speedup 1.0000x reference)
//
#include <hip/hip_runtime.h>
#include <stdint.h>

#pragma clang fp contract(off)

#define BB 32
#define NN 200000
#define N4 50000
#define KK 500
#define KEEPN 100
#define CAND_CAP 4096
#define CONF 0.05f
#define NMSTHR 0.5f
#define CNT_STRIDE 16
#define HBINS 16384
#define HSHIFT 18          // ordkey >> 18 = top 14 bits
#define HSLICES 8          // hist blocks per batch, each owns a private slice

typedef unsigned long long u64;

// ---- workspace layout (bytes) ----
// 0        : hist slices 32*8*16384*4 = 16777216  (plain-store overwritten, no memset)
// 16777216 : cnt  32*16*4 = 2048                  (zeroed by scan_kernel)
// 16779264 : p14  128
// 16779392 : cand 32*4096*8 = 1048576

__device__ __forceinline__ unsigned int ordkey(float s) {
    unsigned int u = __float_as_uint(s);
    return (u & 0x80000000u) ? ~u : (u | 0x80000000u);
}

// ---- 14-bit histogram into PRIVATE per-block slice (no global atomics) ----
__global__ __launch_bounds__(512) void hist_kernel(const float4* __restrict__ ps4,
                                                   unsigned int* __restrict__ hist) {
    __shared__ unsigned int lh[HBINS];
    const int t = threadIdx.x;
    for (int i = t; i < HBINS; i += 512) lh[i] = 0;
    __syncthreads();
    const int b = blockIdx.y, x = blockIdx.x;
    const float4* p = ps4 + (size_t)b * N4;
    for (int i = x * 512 + t; i < N4; i += HSLICES * 512) {
        float4 v = p[i];
        atomicAdd(&lh[ordkey(v.x) >> HSHIFT], 1u);
        atomicAdd(&lh[ordkey(v.y) >> HSHIFT], 1u);
        atomicAdd(&lh[ordkey(v.z) >> HSHIFT], 1u);
        atomicAdd(&lh[ordkey(v.w) >> HSHIFT], 1u);
    }
    __syncthreads();
    uint4* hb4 = (uint4*)(hist + ((size_t)(b * HSLICES + x)) * HBINS);
    for (int i = t; i < HBINS / 4; i += 512) {
        uint4 w;
        w.x = lh[i * 4 + 0]; w.y = lh[i * 4 + 1];
        w.z = lh[i * 4 + 2]; w.w = lh[i * 4 + 3];
        hb4[i] = w;
    }
}

// ---- per-batch: sum 8 slices, find 14-bit prefix crossing KK; zero cnt ----
__global__ __launch_bounds__(1024) void scan_kernel(const unsigned int* __restrict__ hist,
                                                    unsigned int* __restrict__ p14arr,
                                                    unsigned int* __restrict__ cnt) {
    __shared__ unsigned int partial[1024];
    const int t = threadIdx.x, b = blockIdx.x;
    if (t == 0) cnt[b * CNT_STRIDE] = 0;
    const unsigned int* hb = hist + (size_t)b * HSLICES * HBINS;
    unsigned int v[16];
    for (int j = 0; j < 16; ++j) v[j] = 0;
    for (int x = 0; x < HSLICES; ++x) {
        const uint4* hs = (const uint4*)(hb + (size_t)x * HBINS + t * 16);
        for (int j4 = 0; j4 < 4; ++j4) {
            uint4 w = hs[j4];
            v[j4 * 4 + 0] += w.x; v[j4 * 4 + 1] += w.y;
            v[j4 * 4 + 2] += w.z; v[j4 * 4 + 3] += w.w;
        }
    }
    unsigned int tot = 0;
    for (int j = 0; j < 16; ++j) tot += v[j];
    partial[t] = tot;
    __syncthreads();
    for (int d = 1; d < 1024; d <<= 1) {
        unsigned int add = (t + d < 1024) ? partial[t + d] : 0u;
        __syncthreads();
        partial[t] += add;
        __syncthreads();
    }
    unsigned int after = (t < 1023) ? partial[t + 1] : 0u;
    unsigned int sn = after;
    for (int j = 15; j >= 0; --j) {
        unsigned int s = sn + v[j];
        if (s >= (unsigned)KK && sn < (unsigned)KK) p14arr[b] = (unsigned)(t * 16 + j);
        sn = s;
    }
}

// ---- compact candidates (ordered>>18 >= p14): LDS staging, 1 atomic/block ----
__global__ __launch_bounds__(256) void compact_kernel(const float4* __restrict__ ps4,
                                                      const unsigned int* __restrict__ p14arr,
                                                      u64* __restrict__ cand,
                                                      unsigned int* __restrict__ cnt) {
    __shared__ u64 sl[2048];
    __shared__ int lcnt;
    __shared__ unsigned int lbase;
    const int t = threadIdx.x;
    if (t == 0) lcnt = 0;
    __syncthreads();
    const int b = blockIdx.y;
    const unsigned int p14 = p14arr[b];
    const float4* p = ps4 + (size_t)b * N4;
    for (int k = 0; k < 2; ++k) {
        int i4 = blockIdx.x * 512 + k * 256 + t;
        if (i4 < N4) {
            float4 v = p[i4];
            int n = i4 << 2;
            unsigned int u;
            u = ordkey(v.x);
            if ((u >> HSHIFT) >= p14) { int pos = atomicAdd(&lcnt, 1);
                sl[pos] = ((u64)u << 32) | (unsigned int)(~(unsigned int)(n)); }
            u = ordkey(v.y);
            if ((u >> HSHIFT) >= p14) { int pos = atomicAdd(&lcnt, 1);
                sl[pos] = ((u64)u << 32) | (unsigned int)(~(unsigned int)(n + 1)); }
            u = ordkey(v.z);
            if ((u >> HSHIFT) >= p14) { int pos = atomicAdd(&lcnt, 1);
                sl[pos] = ((u64)u << 32) | (unsigned int)(~(unsigned int)(n + 2)); }
            u = ordkey(v.w);
            if ((u >> HSHIFT) >= p14) { int pos = atomicAdd(&lcnt, 1);
                sl[pos] = ((u64)u << 32) | (unsigned int)(~(unsigned int)(n + 3)); }
        }
    }
    __syncthreads();
    if (t == 0 && lcnt > 0) lbase = atomicAdd(&cnt[b * CNT_STRIDE], (unsigned)lcnt);
    __syncthreads();
    for (int i = t; i < lcnt; i += 256) {
        unsigned int pos = lbase + (unsigned)i;
        if (pos < CAND_CAP) cand[(size_t)b * CAND_CAP + pos] = sl[i];
    }
}

// ---- per-batch: radix-select + rank top-500, class-partitioned NMS ----
__global__ __launch_bounds__(1024) void final_kernel(const float* __restrict__ pboxes,
                                                     const int* __restrict__ plabels,
                                                     const u64* __restrict__ cand,
                                                     const unsigned int* __restrict__ cnt,
                                                     float* __restrict__ out) {
    __shared__ u64 kbuf[CAND_CAP];      // keys, later IoU mask rows (500*8)
    __shared__ u64 sel[1024];           // selected keys, then sorted top-500
    __shared__ float sboxes[KK][4];
    __shared__ float sshift[KK][4];
    __shared__ float sscore[KK];
    __shared__ int slabel[KK];
    __shared__ unsigned int h[256];
    __shared__ int clist[KK];
    __shared__ int ccnt[21], coff[22], cfill[21];
    __shared__ u64 validw[8];
    __shared__ int kept[KEEPN];
    __shared__ float wred[16];
    __shared__ u64 s_prefix;
    __shared__ unsigned int s_bin, s_region, s_cntgt;
    __shared__ int s_sc, s_nk;
    __shared__ float s_maxc;

    const int b = blockIdx.x;
    const int tid = threadIdx.x;
    const int lane = tid & 63;

    int m = (int)cnt[b * CNT_STRIDE];
    if (m > CAND_CAP) m = CAND_CAP;

    for (int i = tid; i < m; i += 1024)
        kbuf[i] = cand[(size_t)b * CAND_CAP + i];
    __syncthreads();

    // ---- radix-select: narrow to <=1024 keys >= thr ----
    u64 thr; int seln;
    if (m <= 1024) {
        thr = 0ULL; seln = m;
    } else {
        if (tid == 0) { s_prefix = 0ULL; s_cntgt = 0u; }
        __syncthreads();
        int shift = 56;
        for (; shift >= 0; shift -= 8) {
            if (tid < 256) h[tid] = 0u;
            __syncthreads();
            u64 pref = s_prefix;
            unsigned int cg = s_cntgt;
            for (int i = tid; i < m; i += 1024) {
                u64 k = kbuf[i];
                bool match = (shift == 56) || ((k >> (shift + 8)) == pref);
                if (match) atomicAdd(&h[(unsigned int)((k >> shift) & 0xFF)], 1u);
            }
            __syncthreads();
            for (int d = 1; d < 256; d <<= 1) {
                unsigned int add = (tid < 256 && tid + d < 256) ? h[tid + d] : 0u;
                __syncthreads();
                if (tid < 256) h[tid] += add;
                __syncthreads();
            }
            unsigned int target = (unsigned)KK - cg;
            if (tid < 256) {
                unsigned int st = h[tid];
                unsigned int stn = (tid < 255) ? h[tid + 1] : 0u;
                if (st >= target && stn < target) s_bin = (unsigned)tid;
            }
            __syncthreads();
            if (tid == 0) {
                unsigned int bin = s_bin;
                unsigned int sfx1 = (bin < 255) ? h[bin + 1] : 0u;
                s_region = h[bin] - sfx1;
                s_cntgt = cg + sfx1;
                s_prefix = (shift == 56) ? (u64)bin : ((pref << 8) | (u64)bin);
            }
            __syncthreads();
            if (s_cntgt + s_region <= 1024u) break;
        }
        thr = s_prefix << shift;
        seln = (int)(s_cntgt + s_region);
    }

    // ---- selection: gather keys >= thr into sel[] (wave-aggregated atomic) ----
    if (tid == 0) s_sc = 0;
    __syncthreads();
    for (int r = 0; r < 4; ++r) {
        int i = tid + r * 1024;
        u64 k = (i < m) ? kbuf[i] : 0ULL;
        bool p = (i < m) && (k >= thr);
        u64 mb = __ballot(p);
        int pre = __popcll(mb & ((1ULL << lane) - 1ULL));
        int tot = __popcll(mb);
        int base = 0;
        if (lane == 0 && tot > 0) base = atomicAdd(&s_sc, tot);
        base = __shfl(base, 0);
        if (p) sel[base + pre] = k;
    }
    __syncthreads();

    // ---- brute-force rank (keys unique), scatter sorted top-500 ----
    u64 myk = 0ULL; int myr = 0x7FFFFFFF;
    if (tid < seln) {
        myk = sel[tid];
        int r = 0;
        for (int j = 0; j < seln; ++j) r += (sel[j] > myk) ? 1 : 0;
        myr = r;
    }
    __syncthreads();
    if (tid < seln && myr < KK) sel[myr] = myk;
    __syncthreads();

    // ---- extract, gather boxes/labels ----
    float sc = -1.0f;
    if (tid < KK) {
        u64 key = sel[tid];
        unsigned int lo = (unsigned int)key;
        unsigned int hi = (unsigned int)(key >> 32);
        int idx = (int)(~lo);
        unsigned int bits = (hi & 0x80000000u) ? (hi & 0x7FFFFFFFu) : ~hi;
        sc = __uint_as_float(bits);
        sscore[tid] = sc;
        const float4 bx = *(const float4*)(pboxes + (((size_t)b * NN + (size_t)idx) << 2));
        sboxes[tid][0] = bx.x; sboxes[tid][1] = bx.y;
        sboxes[tid][2] = bx.z; sboxes[tid][3] = bx.w;
        slabel[tid] = plabels[(size_t)b * NN + idx];
    }
    __syncthreads();

    // ---- valid mask + max_coord ----
    bool v = (tid < KK) && (sc > CONF);
    u64 bm = __ballot(v);
    if (lane == 0 && (tid >> 6) < 8) validw[tid >> 6] = bm;
    float lm = 0.0f;
    if (v) lm = fmaxf(fmaxf(sboxes[tid][0], sboxes[tid][1]),
                      fmaxf(sboxes[tid][2], sboxes[tid][3]));
    for (int off = 32; off > 0; off >>= 1) lm = fmaxf(lm, __shfl_down(lm, off));
    if (lane == 0) wred[tid >> 6] = lm;
    __syncthreads();
    if (tid < 64) {
        float x = (tid < 16) ? wred[tid] : 0.0f;
        for (int off = 8; off > 0; off >>= 1) x = fmaxf(x, __shfl_down(x, off));
        if (tid == 0) s_maxc = x;
    }
    __syncthreads();

    // ---- shifted boxes (exact reference arithmetic) ----
    if (tid < KK) {
        float off = (float)slabel[tid] * (s_maxc + 1.0f);
        sshift[tid][0] = sboxes[tid][0] + off;
        sshift[tid][1] = sboxes[tid][1] + off;
        sshift[tid][2] = sboxes[tid][2] + off;
        sshift[tid][3] = sboxes[tid][3] + off;
    }
    // ---- class member lists (cross-label IoU is exactly 0 after offsets) ----
    if (tid < 21) { ccnt[tid] = 0; cfill[tid] = 0; }
    __syncthreads();
    if (tid < KK) atomicAdd(&ccnt[slabel[tid]], 1);
    __syncthreads();
    if (tid == 0) {
        int acc = 0;
        for (int c = 0; c < 21; ++c) { coff[c] = acc; acc += ccnt[c]; }
        coff[21] = acc;
    }
    __syncthreads();
    if (tid < KK) {
        int c = slabel[tid];
        int pos = atomicAdd(&cfill[c], 1);
        clist[coff[c] + pos] = tid;
    }
    for (int i = tid; i < KK * 8; i += 1024) kbuf[i] = 0ULL;
    __syncthreads();

    // ---- IoU > thr bitmask rows: thread i vs same-class members only ----
    if (tid < KK) {
        int c = slabel[tid];
        int n = ccnt[c], base = coff[c];
        float a0 = sshift[tid][0], a1 = sshift[tid][1],
              a2 = sshift[tid][2], a3 = sshift[tid][3];
        float areaA = (a2 - a0) * (a3 - a1);
        for (int q = 0; q < n; ++q) {
            int j = clist[base + q];
            float b0 = sshift[j][0], b1f = sshift[j][1],
                  b2f = sshift[j][2], b3f = sshift[j][3];
            float lt0 = fmaxf(a0, b0), lt1 = fmaxf(a1, b1f);
            float rb0 = fminf(a2, b2f), rb1 = fminf(a3, b3f);
            float ww = fmaxf(rb0 - lt0, 0.0f), hh = fmaxf(rb1 - lt1, 0.0f);
            float inter = ww * hh;
            float areaB = (b2f - b0) * (b3f - b1f);
            float iou = inter / (areaA + areaB - inter);
            if (iou > NMSTHR) kbuf[tid * 8 + (j >> 6)] |= (1ULL << (j & 63));
        }
    }
    __syncthreads();

    // ---- greedy scan on wave 0; early-exit at KEEPN ----
    if (tid < 64) {
        u64 remv = 0ULL;
        u64 vw_reg = (lane < 8) ? validw[lane] : 0ULL;
        int nk = 0;
        for (int i = 0; i < KK && nk < KEEPN; ++i) {
            int w = i >> 6, bpos = i & 63;
            u64 rw = __shfl(remv, w);
            u64 vv = __shfl(vw_reg, w);
            bool alive = (((vv >> bpos) & 1ULL) != 0ULL) && (((rw >> bpos) & 1ULL) == 0ULL);
            if (alive) {
                if (lane == 0) kept[nk] = i;
                u64 roww = (lane < 8) ? kbuf[i * 8 + lane] : 0ULL;
                remv |= roww;
                nk++;
            }
        }
        if (lane == 0) s_nk = nk;
    }
    __syncthreads();

    // ---- outputs (all float32, concatenated in reference return order) ----
    if (tid < KEEPN) {
        const int O_BOX = BB * KEEPN;
        const int O_LAB = BB * KEEPN * 5;
        const int O_SCO = BB * KEEPN * 6;
        const int O_VAL = BB * KEEPN * 7;
        bool q = tid < s_nk;
        int i = q ? kept[tid] : 0;
        int g = b * KEEPN + tid;
        out[g]                 = q ? (float)b : -1.0f;
        out[O_BOX + g * 4 + 0] = q ? sboxes[i][0] : 0.0f;
        out[O_BOX + g * 4 + 1] = q ? sboxes[i][1] : 0.0f;
        out[O_BOX + g * 4 + 2] = q ? sboxes[i][2] : 0.0f;
        out[O_BOX + g * 4 + 3] = q ? sboxes[i][3] : 0.0f;
        out[O_LAB + g]         = q ? (float)slabel[i] : -1.0f;
        out[O_SCO + g]         = q ? sscore[i] : 0.0f;
        out[O_VAL + g]         = q ? 1.0f : 0.0f;
    }
}

extern "C" void kernel_launch(void* const* d_in, const int* in_sizes, int n_in,
                              void* d_out, int out_size, void* d_ws, size_t ws_size,
                              hipStream_t stream) {
    const float* pscores = (const float*)d_in[0];
    const float* pboxes  = (const float*)d_in[1];
    const int*   plabels = (const int*)d_in[2];
    float* out = (float*)d_out;

    uint8_t* ws = (uint8_t*)d_ws;
    unsigned int* hist = (unsigned int*)(ws + 0);
    unsigned int* cnt  = (unsigned int*)(ws + 16777216);
    unsigned int* p14  = (unsigned int*)(ws + 16779264);
    u64*          cand = (u64*)(ws + 16779392);

    hist_kernel<<<dim3(HSLICES, BB), 512, 0, stream>>>((const float4*)pscores, hist);
    scan_kernel<<<BB, 1024, 0, stream>>>(hist, p14, cnt);
    compact_kernel<<<dim3((N4 + 511) / 512, BB), 256, 0, stream>>>(
        (const float4*)pscores, p14, cand, cnt);
    final_kernel<<<BB, 1024, 0, stream>>>(pboxes, plabels, cand, cnt, out);
}